// Round 9
// baseline (477.547 us; speedup 1.0000x reference)
//
#include <hip/hip_runtime.h>

#define NNODES 100000
#define NEDGES 1600000
#define FDIM 128
#define NGRAPHS 128
#define NLAYERS 4
#define NCLASS 10
#define LDA 40      // padded LDS row stride (elems): 80 B = 5*16 B -> 2-way bank alias (free)
#define LDC 136     // epilogue LDS row stride (elems): 272 B, 16B-aligned rows
#define NBUCK 391   // buckets of 256 nodes: dst>>8, 391*256 = 100096 >= 100000
#define EPB 4096    // edges per block in build kernels
#define NBLK_E ((NEDGES + EPB - 1) / EPB)

typedef __attribute__((ext_vector_type(8))) short bf16x8;
typedef __attribute__((ext_vector_type(4))) float f32x4;
typedef unsigned short u16;
typedef unsigned int u32;
typedef unsigned long long u64;

__device__ __forceinline__ u16 f2bf(float f) {
    u32 u = __float_as_uint(f);
    u += 0x7fffu + ((u >> 16) & 1u);   // round-to-nearest-even
    return (u16)(u >> 16);
}
__device__ __forceinline__ float bf_lo(u32 u) { return __uint_as_float(u << 16); }
__device__ __forceinline__ float bf_hi(u32 u) { return __uint_as_float(u & 0xffff0000u); }
__device__ __forceinline__ u32 pack_bf(float a, float b) {
    return (u32)f2bf(a) | ((u32)f2bf(b) << 16);
}

// ---------------- dtype conversion ----------------

__global__ __launch_bounds__(256) void conv_x(const float* __restrict__ x,
                                              u16* __restrict__ xb) {
    int i = (blockIdx.x * 256 + threadIdx.x) * 4;
    if (i < NNODES * FDIM) {
        float4 v = *(const float4*)(x + i);
        u32 p0 = pack_bf(v.x, v.y), p1 = pack_bf(v.z, v.w);
        *(u32*)(xb + i) = p0;
        *(u32*)(xb + i + 2) = p1;
    }
}

// Wcat[l][n][k]: k<128 -> Wrel[k][n], k>=128 -> Wroot[k-128][n]  (transposed, concat)
__global__ __launch_bounds__(256) void conv_w(const float* __restrict__ W1_rel,
                                              const float* __restrict__ W1_root,
                                              const float* __restrict__ Wc_rel,
                                              const float* __restrict__ Wc_root,
                                              u16* __restrict__ Wcat) {
    int idx = blockIdx.x * 256 + threadIdx.x;
    if (idx >= NLAYERS * 256 * FDIM) return;
    int n = idx & 127;
    int k = (idx >> 7) & 255;
    int l = idx >> 15;
    const float* Wr = (l == 0) ? W1_rel  : Wc_rel  + (size_t)(l - 1) * FDIM * FDIM;
    const float* Wt = (l == 0) ? W1_root : Wc_root + (size_t)(l - 1) * FDIM * FDIM;
    float v = (k < 128) ? Wr[(size_t)k * FDIM + n] : Wt[(size_t)(k - 128) * FDIM + n];
    Wcat[(size_t)l * 32768 + (size_t)n * 256 + k] = f2bf(v);
}

// ---------------- graph structure: bucketed CSR build ----------------

__global__ __launch_bounds__(192) void graph_ptr_kernel(const int* __restrict__ batch,
                                                        int* __restrict__ gptr) {
    int g = threadIdx.x;
    if (g > NGRAPHS) return;
    int lo = 0, hi = NNODES;
    while (lo < hi) {
        int mid = (lo + hi) >> 1;
        if (batch[mid] < g) lo = mid + 1; else hi = mid;
    }
    gptr[g] = lo;
}

__global__ __launch_bounds__(256) void bucket_count(const int* __restrict__ dst,
                                                    int* __restrict__ bcount) {
    __shared__ int cnt[NBUCK];
    for (int i = threadIdx.x; i < NBUCK; i += 256) cnt[i] = 0;
    __syncthreads();
    int e0 = blockIdx.x * EPB;
    int e1 = e0 + EPB; if (e1 > NEDGES) e1 = NEDGES;
    for (int e = e0 + threadIdx.x; e < e1; e += 256)
        atomicAdd(&cnt[dst[e] >> 8], 1);
    __syncthreads();
    for (int i = threadIdx.x; i < NBUCK; i += 256)
        if (cnt[i]) atomicAdd(&bcount[i], cnt[i]);
}

__global__ __launch_bounds__(512) void bucket_scan(const int* __restrict__ bcount,
                                                   int* __restrict__ bbase,
                                                   int* __restrict__ bcur,
                                                   int* __restrict__ row_ptr) {
    __shared__ int sd[512];
    int t = threadIdx.x;
    int v = (t < NBUCK) ? bcount[t] : 0;
    sd[t] = v;
    __syncthreads();
    for (int s = 1; s < 512; s <<= 1) {
        int add = (t >= s) ? sd[t - s] : 0;
        __syncthreads();
        sd[t] += add;
        __syncthreads();
    }
    if (t < NBUCK) {
        int excl = sd[t] - v;
        bbase[t] = excl;
        bcur[t] = excl;
    }
    if (t == NBUCK - 1) {
        bbase[NBUCK] = sd[t];
        row_ptr[NNODES] = sd[t];
    }
}

// scatter packed (dst,src) records into per-bucket streams; LDS-aggregated reservations
__global__ __launch_bounds__(256) void bucket_scatter(const int* __restrict__ src,
                                                      const int* __restrict__ dst,
                                                      int* __restrict__ bcur,
                                                      u64* __restrict__ ebuf) {
    __shared__ int cnt[NBUCK];
    for (int i = threadIdx.x; i < NBUCK; i += 256) cnt[i] = 0;
    __syncthreads();
    int e0 = blockIdx.x * EPB;
    int e1 = e0 + EPB; if (e1 > NEDGES) e1 = NEDGES;
    for (int e = e0 + threadIdx.x; e < e1; e += 256)
        atomicAdd(&cnt[dst[e] >> 8], 1);
    __syncthreads();
    for (int i = threadIdx.x; i < NBUCK; i += 256) {
        int c = cnt[i];
        if (c) cnt[i] = atomicAdd(&bcur[i], c);   // cnt[i] becomes the block's base cursor
    }
    __syncthreads();
    for (int e = e0 + threadIdx.x; e < e1; e += 256) {
        int d = dst[e], s = src[e];
        int pos = atomicAdd(&cnt[d >> 8], 1);
        ebuf[pos] = ((u64)(u32)d << 32) | (u32)s;
    }
}

// one block per bucket: local count + scan -> row_ptr; scatter src into bucket's csr slice
__global__ __launch_bounds__(256) void bucket_csr(const u64* __restrict__ ebuf,
                                                  const int* __restrict__ bbase,
                                                  int* __restrict__ row_ptr,
                                                  int* __restrict__ csr) {
    __shared__ int cur[256];
    __shared__ int sd[256];
    int b = blockIdx.x, t = threadIdx.x;
    int ebase = bbase[b], eend = bbase[b + 1];
    int n0 = b << 8;
    cur[t] = 0;
    __syncthreads();
    for (int e = ebase + t; e < eend; e += 256) {
        int d = (int)(ebuf[e] >> 32);
        atomicAdd(&cur[d & 255], 1);
    }
    __syncthreads();
    int v = cur[t];
    sd[t] = v;
    __syncthreads();
    for (int s = 1; s < 256; s <<= 1) {
        int add = (t >= s) ? sd[t - s] : 0;
        __syncthreads();
        sd[t] += add;
        __syncthreads();
    }
    int excl = sd[t] - v;
    cur[t] = ebase + excl;
    if (n0 + t < NNODES) row_ptr[n0 + t] = ebase + excl;
    __syncthreads();
    for (int e = ebase + t; e < eend; e += 256) {
        u64 r = ebuf[e];
        int d = (int)(r >> 32);
        int pos = atomicAdd(&cur[d & 255], 1);
        csr[pos] = (int)(r & 0xffffffffu);
    }
}

// ---------------- aggregation: one wave per node, dwordx4 gather (4 rows / wave-load) ----
// lane l reads 16 B of row idx[4b + (l>>4)] at byte offset (l&15)*16 -> one instruction
// moves 4 complete 256 B rows. Cross-group reduce via shfl_xor(16/32) at the end.

__global__ __launch_bounds__(256) void agg_bf(const u16* __restrict__ h,
                                              const int* __restrict__ row_ptr,
                                              const int* __restrict__ csr,
                                              u16* __restrict__ agg) {
    int wave = threadIdx.x >> 6;
    int lane = threadIdx.x & 63;
    int node = (blockIdx.x << 2) + wave;
    if (node >= NNODES) return;
    int e0 = row_ptr[node], e1 = row_ptr[node + 1];
    int cnt = e1 - e0;
    const int grp = lane >> 4;     // 0..3: which row of the 4-edge batch
    const int sub = lane & 15;     // 0..15: 16B chunk within row

    if (cnt <= 64) {
        float f0 = 0.f, f1 = 0.f, f2 = 0.f, f3 = 0.f;
        float f4 = 0.f, f5 = 0.f, f6 = 0.f, f7 = 0.f;
        int myidx = (lane < cnt) ? csr[e0 + lane] : 0;   // 0 = safe dummy row
        int nb = (cnt + 3) >> 2;
        for (int b = 0; b < nb; ++b) {
            int base = b << 2;
            int i0 = __builtin_amdgcn_readlane(myidx, base);
            int i1 = __builtin_amdgcn_readlane(myidx, base + 1);
            int i2 = __builtin_amdgcn_readlane(myidx, base + 2);
            int i3 = __builtin_amdgcn_readlane(myidx, base + 3);
            int s = (lane & 32) ? ((lane & 16) ? i3 : i2) : ((lane & 16) ? i1 : i0);
            uint4 v = *(const uint4*)(h + (size_t)s * FDIM + sub * 8);
            if (base + 4 <= cnt) {
                f0 += bf_lo(v.x); f1 += bf_hi(v.x);
                f2 += bf_lo(v.y); f3 += bf_hi(v.y);
                f4 += bf_lo(v.z); f5 += bf_hi(v.z);
                f6 += bf_lo(v.w); f7 += bf_hi(v.w);
            } else {
                float m = (base + grp < cnt) ? 1.f : 0.f;
                f0 = fmaf(bf_lo(v.x), m, f0); f1 = fmaf(bf_hi(v.x), m, f1);
                f2 = fmaf(bf_lo(v.y), m, f2); f3 = fmaf(bf_hi(v.y), m, f3);
                f4 = fmaf(bf_lo(v.z), m, f4); f5 = fmaf(bf_hi(v.z), m, f5);
                f6 = fmaf(bf_lo(v.w), m, f6); f7 = fmaf(bf_hi(v.w), m, f7);
            }
        }
        // collapse the 4 lane-groups (bits 4 and 5 of lane)
        f0 += __shfl_xor(f0, 16, 64); f0 += __shfl_xor(f0, 32, 64);
        f1 += __shfl_xor(f1, 16, 64); f1 += __shfl_xor(f1, 32, 64);
        f2 += __shfl_xor(f2, 16, 64); f2 += __shfl_xor(f2, 32, 64);
        f3 += __shfl_xor(f3, 16, 64); f3 += __shfl_xor(f3, 32, 64);
        f4 += __shfl_xor(f4, 16, 64); f4 += __shfl_xor(f4, 32, 64);
        f5 += __shfl_xor(f5, 16, 64); f5 += __shfl_xor(f5, 32, 64);
        f6 += __shfl_xor(f6, 16, 64); f6 += __shfl_xor(f6, 32, 64);
        f7 += __shfl_xor(f7, 16, 64); f7 += __shfl_xor(f7, 32, 64);
        if (lane < 16) {
            uint4 o;
            o.x = pack_bf(f0, f1); o.y = pack_bf(f2, f3);
            o.z = pack_bf(f4, f5); o.w = pack_bf(f6, f7);
            *(uint4*)(agg + (size_t)node * FDIM + sub * 8) = o;
        }
    } else {
        // rare fallback: per-lane u32 gather, 8-deep
        float ax = 0.f, ay = 0.f;
        int e = e0;
        for (; e + 8 <= e1; e += 8) {
            int s0 = csr[e], s1 = csr[e + 1], s2 = csr[e + 2], s3 = csr[e + 3];
            int s4 = csr[e + 4], s5 = csr[e + 5], s6 = csr[e + 6], s7 = csr[e + 7];
            u32 v0 = ((const u32*)(h + (size_t)s0 * FDIM))[lane];
            u32 v1 = ((const u32*)(h + (size_t)s1 * FDIM))[lane];
            u32 v2 = ((const u32*)(h + (size_t)s2 * FDIM))[lane];
            u32 v3 = ((const u32*)(h + (size_t)s3 * FDIM))[lane];
            u32 v4 = ((const u32*)(h + (size_t)s4 * FDIM))[lane];
            u32 v5 = ((const u32*)(h + (size_t)s5 * FDIM))[lane];
            u32 v6 = ((const u32*)(h + (size_t)s6 * FDIM))[lane];
            u32 v7 = ((const u32*)(h + (size_t)s7 * FDIM))[lane];
            ax += bf_lo(v0) + bf_lo(v1) + bf_lo(v2) + bf_lo(v3)
                + bf_lo(v4) + bf_lo(v5) + bf_lo(v6) + bf_lo(v7);
            ay += bf_hi(v0) + bf_hi(v1) + bf_hi(v2) + bf_hi(v3)
                + bf_hi(v4) + bf_hi(v5) + bf_hi(v6) + bf_hi(v7);
        }
        for (; e < e1; ++e) {
            int s0 = csr[e];
            u32 v0 = ((const u32*)(h + (size_t)s0 * FDIM))[lane];
            ax += bf_lo(v0); ay += bf_hi(v0);
        }
        ((u32*)(agg + (size_t)node * FDIM))[lane] = pack_bf(ax, ay);
    }
}

// ---------------- MFMA GEMM + fused mean-pool epilogue ----------------
// relu([agg|h] @ Wcat^T + b) -> hout (bf16), and per-graph sums of the tile into z.
// 128x128 tile, 4 waves (2x2), K=256 in 8 steps of 32. LDS union: Cs aliases As+Bs.

__global__ __launch_bounds__(256) void gemm_mfma(const u16* __restrict__ aggb,
                                                 const u16* __restrict__ hinb,
                                                 const u16* __restrict__ Wl,   // [128 n][256 k]
                                                 const float* __restrict__ bias,
                                                 const int* __restrict__ batch,
                                                 float* __restrict__ z, int layer,
                                                 u16* __restrict__ houtb) {
    __shared__ u16 S[128 * LDC];        // 34816 B; As = S[0..5119], Bs = S[5120..10239], Cs = whole
    __shared__ int batchs[128];
    u16* As = S;
    u16* Bs = S + 128 * LDA;
    const int t = threadIdx.x;
    const int lane = t & 63;
    const int w = t >> 6;
    const int wr = w >> 1, wc = w & 1;
    const int row0 = blockIdx.x * 128;
    const int lr = lane & 15;
    const int lk = (lane >> 4) * 8;

    f32x4 acc[4][4];
#pragma unroll
    for (int m = 0; m < 4; ++m)
#pragma unroll
        for (int n = 0; n < 4; ++n) acc[m][n] = (f32x4){0.f, 0.f, 0.f, 0.f};

    for (int kb = 0; kb < 8; ++kb) {
        const u16* xsrc = (kb < 4) ? aggb : hinb;
        const int koff = (kb & 3) * 32;
#pragma unroll
        for (int it = 0; it < 2; ++it) {
            int u = it * 256 + t;
            int r = u >> 2, c = (u & 3) * 8;
            bf16x8 v = {};
            if (row0 + r < NNODES)
                v = *(const bf16x8*)(xsrc + (size_t)(row0 + r) * FDIM + koff + c);
            *(bf16x8*)&As[r * LDA + c] = v;
        }
#pragma unroll
        for (int it = 0; it < 2; ++it) {
            int u = it * 256 + t;
            int r = u >> 2, c = (u & 3) * 8;
            bf16x8 v = *(const bf16x8*)(Wl + (size_t)r * 256 + kb * 32 + c);
            *(bf16x8*)&Bs[r * LDA + c] = v;
        }
        __syncthreads();
        bf16x8 a[4], b[4];
#pragma unroll
        for (int m = 0; m < 4; ++m)
            a[m] = *(const bf16x8*)&As[(wr * 64 + m * 16 + lr) * LDA + lk];
#pragma unroll
        for (int n = 0; n < 4; ++n)
            b[n] = *(const bf16x8*)&Bs[(wc * 64 + n * 16 + lr) * LDA + lk];
#pragma unroll
        for (int m = 0; m < 4; ++m)
#pragma unroll
            for (int n = 0; n < 4; ++n)
                acc[m][n] = __builtin_amdgcn_mfma_f32_16x16x32_bf16(a[m], b[n], acc[m][n], 0, 0, 0);
        __syncthreads();
    }
    // epilogue: bias + relu + bf16, repack via S (aliased Cs)
#pragma unroll
    for (int m = 0; m < 4; ++m) {
#pragma unroll
        for (int n = 0; n < 4; ++n) {
            int col = wc * 64 + n * 16 + lr;
            float bb = bias[col];
#pragma unroll
            for (int reg = 0; reg < 4; ++reg) {
                int row = wr * 64 + m * 16 + (lane >> 4) * 4 + reg;
                float v = fmaxf(acc[m][n][reg] + bb, 0.f);
                S[row * LDC + col] = f2bf(v);
            }
        }
    }
    if (t < 128) batchs[t] = (row0 + t < NNODES) ? batch[row0 + t] : NGRAPHS;
    __syncthreads();
    // coalesced global store
    {
        int r = t >> 1, half = t & 1;
        if (row0 + r < NNODES) {
#pragma unroll
            for (int j = 0; j < 8; ++j) {
                bf16x8 v = *(const bf16x8*)&S[r * LDC + half * 64 + j * 8];
                *(bf16x8*)(houtb + (size_t)(row0 + r) * FDIM + half * 64 + j * 8) = v;
            }
        }
    }
    // fused pool: 2 threads per column, run-length sums + boundary atomics
    {
        int col = t & 127, half = t >> 7;
        int r0 = half * 64, r1 = r0 + 64;
        float* zl = z + (size_t)layer * FDIM + col;
        int g = batchs[r0];
        float s = 0.f;
        for (int r = r0; r < r1; ++r) {
            int gn = batchs[r];
            if (gn != g) {
                atomicAdd(zl + (size_t)g * (NLAYERS * FDIM), s);
                s = 0.f; g = gn;
            }
            s += __uint_as_float((u32)S[r * LDC + col] << 16);   // bf16 -> f32
        }
        atomicAdd(zl + (size_t)g * (NLAYERS * FDIM), s);
    }
}

// ---------------- final MLP (mean normalization folded into z load) ----------------

__global__ __launch_bounds__(128) void mlp1(const float* __restrict__ z,
                                            const int* __restrict__ gptr,
                                            const float* __restrict__ Wl1,
                                            const float* __restrict__ bl1,
                                            float* __restrict__ z2) {
    int g = blockIdx.x, j = threadIdx.x;
    __shared__ float zs[NLAYERS * FDIM];
    int cnt = gptr[g + 1] - gptr[g]; if (cnt < 1) cnt = 1;
    float invc = 1.0f / (float)cnt;
    for (int k = j; k < NLAYERS * FDIM; k += 128)
        zs[k] = z[(size_t)g * (NLAYERS * FDIM) + k] * invc;
    __syncthreads();
    float s = bl1[j];
    for (int k = 0; k < NLAYERS * FDIM; ++k) s = fmaf(zs[k], Wl1[(size_t)k * FDIM + j], s);
    z2[(size_t)g * FDIM + j] = fmaxf(s, 0.f);
}

__global__ __launch_bounds__(128) void mlp2(const float* __restrict__ z2,
                                            const float* __restrict__ Wl2,
                                            const float* __restrict__ bl2,
                                            float* __restrict__ out) {
    int g = blockIdx.x, c = threadIdx.x;
    __shared__ float zs[FDIM];
    if (threadIdx.x < FDIM) zs[threadIdx.x] = z2[(size_t)g * FDIM + threadIdx.x];
    __syncthreads();
    if (c < NCLASS) {
        float s = bl2[c];
        for (int k = 0; k < FDIM; ++k) s = fmaf(zs[k], Wl2[(size_t)k * NCLASS + c], s);
        out[(size_t)g * NCLASS + c] = s;
    }
}

// ---------------- launch ----------------

extern "C" void kernel_launch(void* const* d_in, const int* in_sizes, int n_in,
                              void* d_out, int out_size, void* d_ws, size_t ws_size,
                              hipStream_t stream) {
    const float* x       = (const float*)d_in[0];
    const int*   ei      = (const int*)d_in[1];
    const int*   batch   = (const int*)d_in[2];
    const float* W1_rel  = (const float*)d_in[3];
    const float* b1_rel  = (const float*)d_in[4];
    const float* W1_root = (const float*)d_in[5];
    const float* Wc_rel  = (const float*)d_in[6];
    const float* bc_rel  = (const float*)d_in[7];
    const float* Wc_root = (const float*)d_in[8];
    const float* Wl1     = (const float*)d_in[9];
    const float* bl1     = (const float*)d_in[10];
    const float* Wl2     = (const float*)d_in[11];
    const float* bl2     = (const float*)d_in[12];
    float* out = (float*)d_out;

    const int* srcv = ei;            // edge_index[0]
    const int* dstv = ei + NEDGES;   // edge_index[1]

    char* ws = (char*)d_ws;
    size_t off = 0;
    auto alloc = [&](size_t bytes) -> void* {
        void* p = ws + off;
        off = (off + bytes + 255) & ~(size_t)255;
        return p;
    };
    u16* xb      = (u16*)alloc((size_t)NNODES * FDIM * 2);
    u16* hA      = (u16*)alloc((size_t)NNODES * FDIM * 2);
    u16* hB      = (u16*)alloc((size_t)NNODES * FDIM * 2);
    u16* aggb    = (u16*)alloc((size_t)NNODES * FDIM * 2);
    u16* Wcat    = (u16*)alloc((size_t)NLAYERS * 256 * FDIM * 2);
    u64* ebuf    = (u64*)alloc((size_t)NEDGES * 8);
    int* csr     = (int*)alloc((size_t)NEDGES * 4);
    int* row_ptr = (int*)alloc((size_t)(NNODES + 1) * 4);
    int* bcount  = (int*)alloc((size_t)(NBUCK + 1) * 4);
    int* bbase   = (int*)alloc((size_t)(NBUCK + 1) * 4);
    int* bcur    = (int*)alloc((size_t)(NBUCK + 1) * 4);
    int* gptr    = (int*)alloc(1024);
    float* z     = (float*)alloc((size_t)(NGRAPHS + 1) * NLAYERS * FDIM * 4);
    float* z2    = (float*)alloc((size_t)NGRAPHS * FDIM * 4);
    (void)ws_size; (void)in_sizes; (void)n_in; (void)out_size;

    hipMemsetAsync(bcount, 0, (size_t)(NBUCK + 1) * 4, stream);
    hipMemsetAsync(z, 0, (size_t)(NGRAPHS + 1) * NLAYERS * FDIM * 4, stream);
    conv_x<<<(NNODES * FDIM / 4 + 255) / 256, 256, 0, stream>>>(x, xb);
    conv_w<<<(NLAYERS * 256 * FDIM + 255) / 256, 256, 0, stream>>>(W1_rel, W1_root, Wc_rel, Wc_root, Wcat);
    graph_ptr_kernel<<<1, 192, 0, stream>>>(batch, gptr);
    bucket_count<<<NBLK_E, 256, 0, stream>>>(dstv, bcount);
    bucket_scan<<<1, 512, 0, stream>>>(bcount, bbase, bcur, row_ptr);
    bucket_scatter<<<NBLK_E, 256, 0, stream>>>(srcv, dstv, bcur, ebuf);
    bucket_csr<<<NBUCK, 256, 0, stream>>>(ebuf, bbase, row_ptr, csr);

    const u16* hin = xb;
    for (int l = 0; l < NLAYERS; ++l) {
        u16* hout = (l & 1) ? hB : hA;
        const u16* Wl = Wcat + (size_t)l * 256 * FDIM;
        const float* bb = (l == 0) ? b1_rel : bc_rel + (size_t)(l - 1) * FDIM;
        agg_bf<<<(NNODES + 3) / 4, 256, 0, stream>>>(hin, row_ptr, csr, aggb);
        gemm_mfma<<<(NNODES + 127) / 128, 256, 0, stream>>>(aggb, hin, Wl, bb, batch, z, l, hout);
        hin = hout;
    }
    mlp1<<<NGRAPHS, 128, 0, stream>>>(z, gptr, Wl1, bl1, z2);
    mlp2<<<NGRAPHS, 128, 0, stream>>>(z2, Wl2, bl2, out);
}

// Round 10
// 454.994 us; speedup vs baseline: 1.0496x; 1.0496x over previous
//
#include <hip/hip_runtime.h>

#define NNODES 100000
#define NEDGES 1600000
#define FDIM 128
#define NGRAPHS 128
#define NLAYERS 4
#define NCLASS 10
#define LDC 136     // epilogue LDS row stride (elems): 272 B, 16B-aligned rows
#define NBUCK 391   // buckets of 256 nodes: dst>>8, 391*256 = 100096 >= 100000
#define EPB 4096    // edges per block in build kernels
#define NBLK_E ((NEDGES + EPB - 1) / EPB)

typedef __attribute__((ext_vector_type(8))) short bf16x8;
typedef __attribute__((ext_vector_type(4))) float f32x4;
typedef unsigned short u16;
typedef unsigned int u32;
typedef unsigned long long u64;

__device__ __forceinline__ u16 f2bf(float f) {
    u32 u = __float_as_uint(f);
    u += 0x7fffu + ((u >> 16) & 1u);   // round-to-nearest-even
    return (u16)(u >> 16);
}
__device__ __forceinline__ float bf_lo(u32 u) { return __uint_as_float(u << 16); }
__device__ __forceinline__ float bf_hi(u32 u) { return __uint_as_float(u & 0xffff0000u); }
__device__ __forceinline__ u32 pack_bf(float a, float b) {
    return (u32)f2bf(a) | ((u32)f2bf(b) << 16);
}

// async global->LDS, 16 B per lane; LDS dest = uniform base + lane*16
__device__ __forceinline__ void gload_lds16(const u16* g, u16* l) {
    __builtin_amdgcn_global_load_lds(
        (const __attribute__((address_space(1))) u32*)g,
        (__attribute__((address_space(3))) u32*)l, 16, 0, 0);
}

// ---------------- dtype conversion ----------------

__global__ __launch_bounds__(256) void conv_x(const float* __restrict__ x,
                                              u16* __restrict__ xb) {
    int i = (blockIdx.x * 256 + threadIdx.x) * 4;
    if (i < NNODES * FDIM) {
        float4 v = *(const float4*)(x + i);
        u32 p0 = pack_bf(v.x, v.y), p1 = pack_bf(v.z, v.w);
        *(u32*)(xb + i) = p0;
        *(u32*)(xb + i + 2) = p1;
    }
}

// Wcat[l][n][k]: k<128 -> Wrel[k][n], k>=128 -> Wroot[k-128][n]  (transposed, concat)
__global__ __launch_bounds__(256) void conv_w(const float* __restrict__ W1_rel,
                                              const float* __restrict__ W1_root,
                                              const float* __restrict__ Wc_rel,
                                              const float* __restrict__ Wc_root,
                                              u16* __restrict__ Wcat) {
    int idx = blockIdx.x * 256 + threadIdx.x;
    if (idx >= NLAYERS * 256 * FDIM) return;
    int n = idx & 127;
    int k = (idx >> 7) & 255;
    int l = idx >> 15;
    const float* Wr = (l == 0) ? W1_rel  : Wc_rel  + (size_t)(l - 1) * FDIM * FDIM;
    const float* Wt = (l == 0) ? W1_root : Wc_root + (size_t)(l - 1) * FDIM * FDIM;
    float v = (k < 128) ? Wr[(size_t)k * FDIM + n] : Wt[(size_t)(k - 128) * FDIM + n];
    Wcat[(size_t)l * 32768 + (size_t)n * 256 + k] = f2bf(v);
}

// ---------------- graph structure: bucketed CSR build ----------------

__global__ __launch_bounds__(192) void graph_ptr_kernel(const int* __restrict__ batch,
                                                        int* __restrict__ gptr) {
    int g = threadIdx.x;
    if (g > NGRAPHS) return;
    int lo = 0, hi = NNODES;
    while (lo < hi) {
        int mid = (lo + hi) >> 1;
        if (batch[mid] < g) lo = mid + 1; else hi = mid;
    }
    gptr[g] = lo;
}

__global__ __launch_bounds__(256) void bucket_count(const int* __restrict__ dst,
                                                    int* __restrict__ bcount) {
    __shared__ int cnt[NBUCK];
    for (int i = threadIdx.x; i < NBUCK; i += 256) cnt[i] = 0;
    __syncthreads();
    int e0 = blockIdx.x * EPB;
    int e1 = e0 + EPB; if (e1 > NEDGES) e1 = NEDGES;
    for (int e = e0 + threadIdx.x; e < e1; e += 256)
        atomicAdd(&cnt[dst[e] >> 8], 1);
    __syncthreads();
    for (int i = threadIdx.x; i < NBUCK; i += 256)
        if (cnt[i]) atomicAdd(&bcount[i], cnt[i]);
}

__global__ __launch_bounds__(512) void bucket_scan(const int* __restrict__ bcount,
                                                   int* __restrict__ bbase,
                                                   int* __restrict__ bcur,
                                                   int* __restrict__ row_ptr) {
    __shared__ int sd[512];
    int t = threadIdx.x;
    int v = (t < NBUCK) ? bcount[t] : 0;
    sd[t] = v;
    __syncthreads();
    for (int s = 1; s < 512; s <<= 1) {
        int add = (t >= s) ? sd[t - s] : 0;
        __syncthreads();
        sd[t] += add;
        __syncthreads();
    }
    if (t < NBUCK) {
        int excl = sd[t] - v;
        bbase[t] = excl;
        bcur[t] = excl;
    }
    if (t == NBUCK - 1) {
        bbase[NBUCK] = sd[t];
        row_ptr[NNODES] = sd[t];
    }
}

// scatter packed (dst,src) records into per-bucket streams; LDS-aggregated reservations
__global__ __launch_bounds__(256) void bucket_scatter(const int* __restrict__ src,
                                                      const int* __restrict__ dst,
                                                      int* __restrict__ bcur,
                                                      u64* __restrict__ ebuf) {
    __shared__ int cnt[NBUCK];
    for (int i = threadIdx.x; i < NBUCK; i += 256) cnt[i] = 0;
    __syncthreads();
    int e0 = blockIdx.x * EPB;
    int e1 = e0 + EPB; if (e1 > NEDGES) e1 = NEDGES;
    for (int e = e0 + threadIdx.x; e < e1; e += 256)
        atomicAdd(&cnt[dst[e] >> 8], 1);
    __syncthreads();
    for (int i = threadIdx.x; i < NBUCK; i += 256) {
        int c = cnt[i];
        if (c) cnt[i] = atomicAdd(&bcur[i], c);   // cnt[i] becomes the block's base cursor
    }
    __syncthreads();
    for (int e = e0 + threadIdx.x; e < e1; e += 256) {
        int d = dst[e], s = src[e];
        int pos = atomicAdd(&cnt[d >> 8], 1);
        ebuf[pos] = ((u64)(u32)d << 32) | (u32)s;
    }
}

// one block per bucket: local count + scan -> row_ptr; scatter src into bucket's csr slice
__global__ __launch_bounds__(256) void bucket_csr(const u64* __restrict__ ebuf,
                                                  const int* __restrict__ bbase,
                                                  int* __restrict__ row_ptr,
                                                  int* __restrict__ csr) {
    __shared__ int cur[256];
    __shared__ int sd[256];
    int b = blockIdx.x, t = threadIdx.x;
    int ebase = bbase[b], eend = bbase[b + 1];
    int n0 = b << 8;
    cur[t] = 0;
    __syncthreads();
    for (int e = ebase + t; e < eend; e += 256) {
        int d = (int)(ebuf[e] >> 32);
        atomicAdd(&cur[d & 255], 1);
    }
    __syncthreads();
    int v = cur[t];
    sd[t] = v;
    __syncthreads();
    for (int s = 1; s < 256; s <<= 1) {
        int add = (t >= s) ? sd[t - s] : 0;
        __syncthreads();
        sd[t] += add;
        __syncthreads();
    }
    int excl = sd[t] - v;
    cur[t] = ebase + excl;
    if (n0 + t < NNODES) row_ptr[n0 + t] = ebase + excl;
    __syncthreads();
    for (int e = ebase + t; e < eend; e += 256) {
        u64 r = ebuf[e];
        int d = (int)(r >> 32);
        int pos = atomicAdd(&cur[d & 255], 1);
        csr[pos] = (int)(r & 0xffffffffu);
    }
}

// ---------------- aggregation: one wave per node, scalar-indexed gather (r8 version) -----

__global__ __launch_bounds__(256) void agg_bf(const u16* __restrict__ h,
                                              const int* __restrict__ row_ptr,
                                              const int* __restrict__ csr,
                                              u16* __restrict__ agg) {
    int wave = threadIdx.x >> 6;
    int lane = threadIdx.x & 63;
    int node = (blockIdx.x << 2) + wave;
    if (node >= NNODES) return;
    int e0 = row_ptr[node], e1 = row_ptr[node + 1];
    int cnt = e1 - e0;
    float ax = 0.f, ay = 0.f;
    if (cnt <= 64) {
        int myidx = (lane < cnt) ? csr[e0 + lane] : 0;
        int nb = (cnt + 15) >> 4;
        for (int b = 0; b < nb; ++b) {
            int base = b * 16;
            u32 vv[16];
#pragma unroll
            for (int i = 0; i < 16; ++i) {
                int s = __builtin_amdgcn_readlane(myidx, base + i);
                vv[i] = ((const u32*)(h + (size_t)s * FDIM))[lane];
            }
            if (base + 16 <= cnt) {
#pragma unroll
                for (int i = 0; i < 16; ++i) { ax += bf_lo(vv[i]); ay += bf_hi(vv[i]); }
            } else {
#pragma unroll
                for (int i = 0; i < 16; ++i) {
                    float m = (base + i < cnt) ? 1.f : 0.f;
                    ax = fmaf(bf_lo(vv[i]), m, ax);
                    ay = fmaf(bf_hi(vv[i]), m, ay);
                }
            }
        }
    } else {
        int e = e0;
        for (; e + 8 <= e1; e += 8) {
            int s0 = csr[e], s1 = csr[e + 1], s2 = csr[e + 2], s3 = csr[e + 3];
            int s4 = csr[e + 4], s5 = csr[e + 5], s6 = csr[e + 6], s7 = csr[e + 7];
            u32 v0 = ((const u32*)(h + (size_t)s0 * FDIM))[lane];
            u32 v1 = ((const u32*)(h + (size_t)s1 * FDIM))[lane];
            u32 v2 = ((const u32*)(h + (size_t)s2 * FDIM))[lane];
            u32 v3 = ((const u32*)(h + (size_t)s3 * FDIM))[lane];
            u32 v4 = ((const u32*)(h + (size_t)s4 * FDIM))[lane];
            u32 v5 = ((const u32*)(h + (size_t)s5 * FDIM))[lane];
            u32 v6 = ((const u32*)(h + (size_t)s6 * FDIM))[lane];
            u32 v7 = ((const u32*)(h + (size_t)s7 * FDIM))[lane];
            ax += bf_lo(v0) + bf_lo(v1) + bf_lo(v2) + bf_lo(v3)
                + bf_lo(v4) + bf_lo(v5) + bf_lo(v6) + bf_lo(v7);
            ay += bf_hi(v0) + bf_hi(v1) + bf_hi(v2) + bf_hi(v3)
                + bf_hi(v4) + bf_hi(v5) + bf_hi(v6) + bf_hi(v7);
        }
        for (; e < e1; ++e) {
            int s0 = csr[e];
            u32 v0 = ((const u32*)(h + (size_t)s0 * FDIM))[lane];
            ax += bf_lo(v0); ay += bf_hi(v0);
        }
    }
    ((u32*)(agg + (size_t)node * FDIM))[lane] = pack_bf(ax, ay);
}

// ---------------- MFMA GEMM (global_load_lds staging) + fused mean-pool epilogue ---------
// relu([agg|h] @ Wcat^T + b) -> hout (bf16), per-graph sums into z.
// 128x128 tile, 4 waves (2x2), K=256 in 8 steps of 32.
// A/B staged via global_load_lds width-16 into LINEAR [128][32] LDS tiles with XOR
// chunk-swizzle (chunk ^= (row>>1)&3) applied on SOURCE and READ (rule: both sides).
// Read bank pattern: 2-way aliasing (free). Cs (epilogue) aliases As+Bs.

__global__ __launch_bounds__(256) void gemm_mfma(const u16* __restrict__ aggb,
                                                 const u16* __restrict__ hinb,
                                                 const u16* __restrict__ Wl,   // [128 n][256 k]
                                                 const float* __restrict__ bias,
                                                 const int* __restrict__ batch,
                                                 float* __restrict__ z, int layer,
                                                 u16* __restrict__ houtb) {
    __shared__ u16 S[128 * LDC];        // 34816 B; As=S[0..4095], Bs=S[4096..8191], Cs=whole
    __shared__ int batchs[128];
    u16* As = S;                        // [128][32] linear bf16, swizzled chunks
    u16* Bs = S + 4096;
    const int t = threadIdx.x;
    const int lane = t & 63;
    const int w = t >> 6;
    const int wr = w >> 1, wc = w & 1;
    const int row0 = blockIdx.x * 128;
    const int lr = lane & 15;
    const int qread = lane >> 4;        // 16B chunk index 0..3 (= old lk/8)

    // staging lane geometry (per 16-row sub-tile): lane -> row (l>>2), chunk (l&3)
    const int srow_in = lane >> 2;      // 0..15
    const int sq = lane & 3;

    f32x4 acc[4][4];
#pragma unroll
    for (int m = 0; m < 4; ++m)
#pragma unroll
        for (int n = 0; n < 4; ++n) acc[m][n] = (f32x4){0.f, 0.f, 0.f, 0.f};

    for (int kb = 0; kb < 8; ++kb) {
        const u16* xsrc = (kb < 4) ? aggb : hinb;
        const int koff = (kb & 3) * 32;
#pragma unroll
        for (int i = 0; i < 2; ++i) {
            int blk16 = w * 2 + i;               // 0..7: which 16-row sub-tile
            int r = blk16 * 16 + srow_in;        // 0..127
            int sc = sq ^ ((r >> 1) & 3);        // inverse-swizzled source chunk
            int arow = row0 + r; if (arow > NNODES - 1) arow = NNODES - 1;  // clamp (OOB rows unused)
            gload_lds16(xsrc + (size_t)arow * FDIM + koff + sc * 8, As + blk16 * 512);
            gload_lds16(Wl + (size_t)r * 256 + kb * 32 + sc * 8, Bs + blk16 * 512);
        }
        __syncthreads();                         // drains vmcnt -> LDS tiles ready
        bf16x8 a[4], b[4];
#pragma unroll
        for (int m = 0; m < 4; ++m) {
            int r = wr * 64 + m * 16 + lr;
            int ch = qread ^ ((r >> 1) & 3);     // swizzled read chunk
            a[m] = *(const bf16x8*)&As[r * 32 + ch * 8];
        }
#pragma unroll
        for (int n = 0; n < 4; ++n) {
            int r = wc * 64 + n * 16 + lr;
            int ch = qread ^ ((r >> 1) & 3);
            b[n] = *(const bf16x8*)&Bs[r * 32 + ch * 8];
        }
#pragma unroll
        for (int m = 0; m < 4; ++m)
#pragma unroll
            for (int n = 0; n < 4; ++n)
                acc[m][n] = __builtin_amdgcn_mfma_f32_16x16x32_bf16(a[m], b[n], acc[m][n], 0, 0, 0);
        __syncthreads();
    }
    // epilogue: bias + relu + bf16, repack via S (aliased Cs)
#pragma unroll
    for (int m = 0; m < 4; ++m) {
#pragma unroll
        for (int n = 0; n < 4; ++n) {
            int col = wc * 64 + n * 16 + lr;
            float bb = bias[col];
#pragma unroll
            for (int reg = 0; reg < 4; ++reg) {
                int row = wr * 64 + m * 16 + (lane >> 4) * 4 + reg;
                float v = fmaxf(acc[m][n][reg] + bb, 0.f);
                S[row * LDC + col] = f2bf(v);
            }
        }
    }
    if (t < 128) batchs[t] = (row0 + t < NNODES) ? batch[row0 + t] : NGRAPHS;
    __syncthreads();
    // coalesced global store
    {
        int r = t >> 1, half = t & 1;
        if (row0 + r < NNODES) {
#pragma unroll
            for (int j = 0; j < 8; ++j) {
                bf16x8 v = *(const bf16x8*)&S[r * LDC + half * 64 + j * 8];
                *(bf16x8*)(houtb + (size_t)(row0 + r) * FDIM + half * 64 + j * 8) = v;
            }
        }
    }
    // fused pool: 2 threads per column, run-length sums + boundary atomics
    {
        int col = t & 127, half = t >> 7;
        int r0 = half * 64, r1 = r0 + 64;
        float* zl = z + (size_t)layer * FDIM + col;
        int g = batchs[r0];
        float s = 0.f;
        for (int r = r0; r < r1; ++r) {
            int gn = batchs[r];
            if (gn != g) {
                atomicAdd(zl + (size_t)g * (NLAYERS * FDIM), s);
                s = 0.f; g = gn;
            }
            s += __uint_as_float((u32)S[r * LDC + col] << 16);   // bf16 -> f32
        }
        atomicAdd(zl + (size_t)g * (NLAYERS * FDIM), s);
    }
}

// ---------------- final MLP (mean normalization folded into z load) ----------------

__global__ __launch_bounds__(128) void mlp1(const float* __restrict__ z,
                                            const int* __restrict__ gptr,
                                            const float* __restrict__ Wl1,
                                            const float* __restrict__ bl1,
                                            float* __restrict__ z2) {
    int g = blockIdx.x, j = threadIdx.x;
    __shared__ float zs[NLAYERS * FDIM];
    int cnt = gptr[g + 1] - gptr[g]; if (cnt < 1) cnt = 1;
    float invc = 1.0f / (float)cnt;
    for (int k = j; k < NLAYERS * FDIM; k += 128)
        zs[k] = z[(size_t)g * (NLAYERS * FDIM) + k] * invc;
    __syncthreads();
    float s = bl1[j];
    for (int k = 0; k < NLAYERS * FDIM; ++k) s = fmaf(zs[k], Wl1[(size_t)k * FDIM + j], s);
    z2[(size_t)g * FDIM + j] = fmaxf(s, 0.f);
}

__global__ __launch_bounds__(128) void mlp2(const float* __restrict__ z2,
                                            const float* __restrict__ Wl2,
                                            const float* __restrict__ bl2,
                                            float* __restrict__ out) {
    int g = blockIdx.x, c = threadIdx.x;
    __shared__ float zs[FDIM];
    if (threadIdx.x < FDIM) zs[threadIdx.x] = z2[(size_t)g * FDIM + threadIdx.x];
    __syncthreads();
    if (c < NCLASS) {
        float s = bl2[c];
        for (int k = 0; k < FDIM; ++k) s = fmaf(zs[k], Wl2[(size_t)k * NCLASS + c], s);
        out[(size_t)g * NCLASS + c] = s;
    }
}

// ---------------- launch ----------------

extern "C" void kernel_launch(void* const* d_in, const int* in_sizes, int n_in,
                              void* d_out, int out_size, void* d_ws, size_t ws_size,
                              hipStream_t stream) {
    const float* x       = (const float*)d_in[0];
    const int*   ei      = (const int*)d_in[1];
    const int*   batch   = (const int*)d_in[2];
    const float* W1_rel  = (const float*)d_in[3];
    const float* b1_rel  = (const float*)d_in[4];
    const float* W1_root = (const float*)d_in[5];
    const float* Wc_rel  = (const float*)d_in[6];
    const float* bc_rel  = (const float*)d_in[7];
    const float* Wc_root = (const float*)d_in[8];
    const float* Wl1     = (const float*)d_in[9];
    const float* bl1     = (const float*)d_in[10];
    const float* Wl2     = (const float*)d_in[11];
    const float* bl2     = (const float*)d_in[12];
    float* out = (float*)d_out;

    const int* srcv = ei;            // edge_index[0]
    const int* dstv = ei + NEDGES;   // edge_index[1]

    char* ws = (char*)d_ws;
    size_t off = 0;
    auto alloc = [&](size_t bytes) -> void* {
        void* p = ws + off;
        off = (off + bytes + 255) & ~(size_t)255;
        return p;
    };
    u16* xb      = (u16*)alloc((size_t)NNODES * FDIM * 2);
    u16* hA      = (u16*)alloc((size_t)NNODES * FDIM * 2);
    u16* hB      = (u16*)alloc((size_t)NNODES * FDIM * 2);
    u16* aggb    = (u16*)alloc((size_t)NNODES * FDIM * 2);
    u16* Wcat    = (u16*)alloc((size_t)NLAYERS * 256 * FDIM * 2);
    u64* ebuf    = (u64*)alloc((size_t)NEDGES * 8);
    int* csr     = (int*)alloc((size_t)NEDGES * 4);
    int* row_ptr = (int*)alloc((size_t)(NNODES + 1) * 4);
    int* bcount  = (int*)alloc((size_t)(NBUCK + 1) * 4);
    int* bbase   = (int*)alloc((size_t)(NBUCK + 1) * 4);
    int* bcur    = (int*)alloc((size_t)(NBUCK + 1) * 4);
    int* gptr    = (int*)alloc(1024);
    float* z     = (float*)alloc((size_t)(NGRAPHS + 1) * NLAYERS * FDIM * 4);
    float* z2    = (float*)alloc((size_t)NGRAPHS * FDIM * 4);
    (void)ws_size; (void)in_sizes; (void)n_in; (void)out_size;

    hipMemsetAsync(bcount, 0, (size_t)(NBUCK + 1) * 4, stream);
    hipMemsetAsync(z, 0, (size_t)(NGRAPHS + 1) * NLAYERS * FDIM * 4, stream);
    conv_x<<<(NNODES * FDIM / 4 + 255) / 256, 256, 0, stream>>>(x, xb);
    conv_w<<<(NLAYERS * 256 * FDIM + 255) / 256, 256, 0, stream>>>(W1_rel, W1_root, Wc_rel, Wc_root, Wcat);
    graph_ptr_kernel<<<1, 192, 0, stream>>>(batch, gptr);
    bucket_count<<<NBLK_E, 256, 0, stream>>>(dstv, bcount);
    bucket_scan<<<1, 512, 0, stream>>>(bcount, bbase, bcur, row_ptr);
    bucket_scatter<<<NBLK_E, 256, 0, stream>>>(srcv, dstv, bcur, ebuf);
    bucket_csr<<<NBUCK, 256, 0, stream>>>(ebuf, bbase, row_ptr, csr);

    const u16* hin = xb;
    for (int l = 0; l < NLAYERS; ++l) {
        u16* hout = (l & 1) ? hB : hA;
        const u16* Wl = Wcat + (size_t)l * 256 * FDIM;
        const float* bb = (l == 0) ? b1_rel : bc_rel + (size_t)(l - 1) * FDIM;
        agg_bf<<<(NNODES + 3) / 4, 256, 0, stream>>>(hin, row_ptr, csr, aggb);
        gemm_mfma<<<(NNODES + 127) / 128, 256, 0, stream>>>(aggb, hin, Wl, bb, batch, z, l, hout);
        hin = hout;
    }
    mlp1<<<NGRAPHS, 128, 0, stream>>>(z, gptr, Wl1, bl1, z2);
    mlp2<<<NGRAPHS, 128, 0, stream>>>(z2, Wl2, bl2, out);
}

// Round 11
// 437.870 us; speedup vs baseline: 1.0906x; 1.0391x over previous
//
#include <hip/hip_runtime.h>

#define NNODES 100000
#define NEDGES 1600000
#define FDIM 128
#define NGRAPHS 128
#define NLAYERS 4
#define NCLASS 10
#define LDC 136     // epilogue LDS row stride (elems): 272 B, 16B-aligned rows
#define NBUCK 391   // buckets of 256 nodes: dst>>8, 391*256 = 100096 >= 100000
#define EBCAP 5120  // per-bucket edge capacity: mean 4090, sigma 64 -> +16 sigma
#define EPB 4096    // edges per block in scatter kernel
#define NBLK_E ((NEDGES + EPB - 1) / EPB)

typedef __attribute__((ext_vector_type(8))) short bf16x8;
typedef __attribute__((ext_vector_type(4))) float f32x4;
typedef unsigned short u16;
typedef unsigned int u32;
typedef unsigned long long u64;

__device__ __forceinline__ u16 f2bf(float f) {
    u32 u = __float_as_uint(f);
    u += 0x7fffu + ((u >> 16) & 1u);   // round-to-nearest-even
    return (u16)(u >> 16);
}
__device__ __forceinline__ float bf_lo(u32 u) { return __uint_as_float(u << 16); }
__device__ __forceinline__ float bf_hi(u32 u) { return __uint_as_float(u & 0xffff0000u); }
__device__ __forceinline__ u32 pack_bf(float a, float b) {
    return (u32)f2bf(a) | ((u32)f2bf(b) << 16);
}

// async global->LDS, 16 B per lane; LDS dest = uniform base + lane*16
__device__ __forceinline__ void gload_lds16(const u16* g, u16* l) {
    __builtin_amdgcn_global_load_lds(
        (const __attribute__((address_space(1))) u32*)g,
        (__attribute__((address_space(3))) u32*)l, 16, 0, 0);
}

// ---------------- dtype conversion ----------------

__global__ __launch_bounds__(256) void conv_x(const float* __restrict__ x,
                                              u16* __restrict__ xb) {
    int i = (blockIdx.x * 256 + threadIdx.x) * 4;
    if (i < NNODES * FDIM) {
        float4 v = *(const float4*)(x + i);
        u32 p0 = pack_bf(v.x, v.y), p1 = pack_bf(v.z, v.w);
        *(u32*)(xb + i) = p0;
        *(u32*)(xb + i + 2) = p1;
    }
}

// Wcat[l][n][k]: k<128 -> Wrel[k][n], k>=128 -> Wroot[k-128][n]  (transposed, concat)
__global__ __launch_bounds__(256) void conv_w(const float* __restrict__ W1_rel,
                                              const float* __restrict__ W1_root,
                                              const float* __restrict__ Wc_rel,
                                              const float* __restrict__ Wc_root,
                                              u16* __restrict__ Wcat) {
    int idx = blockIdx.x * 256 + threadIdx.x;
    if (idx >= NLAYERS * 256 * FDIM) return;
    int n = idx & 127;
    int k = (idx >> 7) & 255;
    int l = idx >> 15;
    const float* Wr = (l == 0) ? W1_rel  : Wc_rel  + (size_t)(l - 1) * FDIM * FDIM;
    const float* Wt = (l == 0) ? W1_root : Wc_root + (size_t)(l - 1) * FDIM * FDIM;
    float v = (k < 128) ? Wr[(size_t)k * FDIM + n] : Wt[(size_t)(k - 128) * FDIM + n];
    Wcat[(size_t)l * 32768 + (size_t)n * 256 + k] = f2bf(v);
}

// ---------------- graph structure: single-pass bucketed CSR build ----------------

__global__ __launch_bounds__(192) void graph_ptr_kernel(const int* __restrict__ batch,
                                                        int* __restrict__ gptr) {
    int g = threadIdx.x;
    if (g > NGRAPHS) return;
    int lo = 0, hi = NNODES;
    while (lo < hi) {
        int mid = (lo + hi) >> 1;
        if (batch[mid] < g) lo = mid + 1; else hi = mid;
    }
    gptr[g] = lo;
}

__global__ __launch_bounds__(256) void bcur_init(int* __restrict__ bcur) {
    int i = blockIdx.x * 256 + threadIdx.x;
    if (i < NBUCK) bcur[i] = i * EBCAP;
}

// scatter packed (dst,src) records into fixed-capacity per-bucket streams
__global__ __launch_bounds__(256) void bucket_scatter(const int* __restrict__ src,
                                                      const int* __restrict__ dst,
                                                      int* __restrict__ bcur,
                                                      u64* __restrict__ ebuf) {
    __shared__ int cnt[NBUCK];
    for (int i = threadIdx.x; i < NBUCK; i += 256) cnt[i] = 0;
    __syncthreads();
    int e0 = blockIdx.x * EPB;
    int e1 = e0 + EPB; if (e1 > NEDGES) e1 = NEDGES;
    for (int e = e0 + threadIdx.x; e < e1; e += 256)
        atomicAdd(&cnt[dst[e] >> 8], 1);
    __syncthreads();
    for (int i = threadIdx.x; i < NBUCK; i += 256) {
        int c = cnt[i];
        if (c) cnt[i] = atomicAdd(&bcur[i], c);   // cnt[i] becomes the block's base cursor
    }
    __syncthreads();
    for (int e = e0 + threadIdx.x; e < e1; e += 256) {
        int d = dst[e], s = src[e];
        int pos = atomicAdd(&cnt[d >> 8], 1);
        ebuf[pos] = ((u64)(u32)d << 32) | (u32)s;
    }
}

// one block per bucket: local count + scan -> rowstart/rowend; scatter src into csr slice
__global__ __launch_bounds__(256) void bucket_csr(const u64* __restrict__ ebuf,
                                                  const int* __restrict__ bcur,
                                                  int* __restrict__ rowstart,
                                                  int* __restrict__ rowend,
                                                  int* __restrict__ csr) {
    __shared__ int cur[256];
    __shared__ int sd[256];
    int b = blockIdx.x, t = threadIdx.x;
    int ebase = b * EBCAP, eend = bcur[b];
    int n0 = b << 8;
    cur[t] = 0;
    __syncthreads();
    for (int e = ebase + t; e < eend; e += 256) {
        int d = (int)(ebuf[e] >> 32);
        atomicAdd(&cur[d & 255], 1);
    }
    __syncthreads();
    int v = cur[t];
    sd[t] = v;
    __syncthreads();
    for (int s = 1; s < 256; s <<= 1) {
        int add = (t >= s) ? sd[t - s] : 0;
        __syncthreads();
        sd[t] += add;
        __syncthreads();
    }
    int excl = sd[t] - v;
    cur[t] = ebase + excl;
    if (n0 + t < NNODES) {
        rowstart[n0 + t] = ebase + excl;
        rowend[n0 + t]   = ebase + excl + v;
    }
    __syncthreads();
    for (int e = ebase + t; e < eend; e += 256) {
        u64 r = ebuf[e];
        int d = (int)(r >> 32);
        int pos = atomicAdd(&cur[d & 255], 1);
        csr[pos] = (int)(r & 0xffffffffu);
    }
}

// ---------------- aggregation: one wave per node, scalar-indexed gather ----------------

__global__ __launch_bounds__(256) void agg_bf(const u16* __restrict__ h,
                                              const int* __restrict__ rowstart,
                                              const int* __restrict__ rowend,
                                              const int* __restrict__ csr,
                                              u16* __restrict__ agg) {
    int wave = threadIdx.x >> 6;
    int lane = threadIdx.x & 63;
    int node = (blockIdx.x << 2) + wave;
    if (node >= NNODES) return;
    int e0 = rowstart[node], e1 = rowend[node];
    int cnt = e1 - e0;
    float ax = 0.f, ay = 0.f;
    if (cnt <= 64) {
        int myidx = (lane < cnt) ? csr[e0 + lane] : 0;
        int nb = (cnt + 15) >> 4;
        for (int b = 0; b < nb; ++b) {
            int base = b * 16;
            u32 vv[16];
#pragma unroll
            for (int i = 0; i < 16; ++i) {
                int s = __builtin_amdgcn_readlane(myidx, base + i);
                vv[i] = ((const u32*)(h + (size_t)s * FDIM))[lane];
            }
            if (base + 16 <= cnt) {
#pragma unroll
                for (int i = 0; i < 16; ++i) { ax += bf_lo(vv[i]); ay += bf_hi(vv[i]); }
            } else {
#pragma unroll
                for (int i = 0; i < 16; ++i) {
                    float m = (base + i < cnt) ? 1.f : 0.f;
                    ax = fmaf(bf_lo(vv[i]), m, ax);
                    ay = fmaf(bf_hi(vv[i]), m, ay);
                }
            }
        }
    } else {
        int e = e0;
        for (; e + 8 <= e1; e += 8) {
            int s0 = csr[e], s1 = csr[e + 1], s2 = csr[e + 2], s3 = csr[e + 3];
            int s4 = csr[e + 4], s5 = csr[e + 5], s6 = csr[e + 6], s7 = csr[e + 7];
            u32 v0 = ((const u32*)(h + (size_t)s0 * FDIM))[lane];
            u32 v1 = ((const u32*)(h + (size_t)s1 * FDIM))[lane];
            u32 v2 = ((const u32*)(h + (size_t)s2 * FDIM))[lane];
            u32 v3 = ((const u32*)(h + (size_t)s3 * FDIM))[lane];
            u32 v4 = ((const u32*)(h + (size_t)s4 * FDIM))[lane];
            u32 v5 = ((const u32*)(h + (size_t)s5 * FDIM))[lane];
            u32 v6 = ((const u32*)(h + (size_t)s6 * FDIM))[lane];
            u32 v7 = ((const u32*)(h + (size_t)s7 * FDIM))[lane];
            ax += bf_lo(v0) + bf_lo(v1) + bf_lo(v2) + bf_lo(v3)
                + bf_lo(v4) + bf_lo(v5) + bf_lo(v6) + bf_lo(v7);
            ay += bf_hi(v0) + bf_hi(v1) + bf_hi(v2) + bf_hi(v3)
                + bf_hi(v4) + bf_hi(v5) + bf_hi(v6) + bf_hi(v7);
        }
        for (; e < e1; ++e) {
            int s0 = csr[e];
            u32 v0 = ((const u32*)(h + (size_t)s0 * FDIM))[lane];
            ax += bf_lo(v0); ay += bf_hi(v0);
        }
    }
    ((u32*)(agg + (size_t)node * FDIM))[lane] = pack_bf(ax, ay);
}

// ---------------- MFMA GEMM (BK=64, global_load_lds staging) + fused pool ---------------
// relu([agg|h] @ Wcat^T + b) -> hout (bf16), per-graph sums into z.
// 128x128 tile, 4 waves (2x2), K=256 in 4 steps of 64 (2 MFMA sub-steps each).
// A/B staged via global_load_lds width-16 into linear [128][64] LDS tiles with XOR
// chunk-swizzle (chunk ^= row&7) applied on SOURCE and READ. Read = 2-way alias (free).
// Cs (epilogue, LDC stride) aliases As+Bs.

__global__ __launch_bounds__(256) void gemm_mfma(const u16* __restrict__ aggb,
                                                 const u16* __restrict__ hinb,
                                                 const u16* __restrict__ Wl,   // [128 n][256 k]
                                                 const float* __restrict__ bias,
                                                 const int* __restrict__ batch,
                                                 float* __restrict__ z, int layer,
                                                 u16* __restrict__ houtb) {
    __shared__ u16 S[128 * LDC];        // 34816 B; As=S[0..8191], Bs=S[8192..16383], Cs=whole
    __shared__ int batchs[128];
    u16* As = S;                        // [128][64] bf16, swizzled 16B chunks
    u16* Bs = S + 8192;
    const int t = threadIdx.x;
    const int lane = t & 63;
    const int w = t >> 6;
    const int wr = w >> 1, wc = w & 1;
    const int row0 = blockIdx.x * 128;
    const int lr = lane & 15;

    const int srow = lane >> 3;         // staging: row 0..7 within 8-row group
    const int sq = lane & 7;            // staging: chunk slot 0..7

    f32x4 acc[4][4];
#pragma unroll
    for (int m = 0; m < 4; ++m)
#pragma unroll
        for (int n = 0; n < 4; ++n) acc[m][n] = (f32x4){0.f, 0.f, 0.f, 0.f};

    for (int kb = 0; kb < 4; ++kb) {
        const u16* xsrc = (kb < 2) ? aggb : hinb;
        const int koff = (kb & 1) * 64;
#pragma unroll
        for (int i = 0; i < 4; ++i) {
            int blk8 = w * 4 + i;               // 0..15: which 8-row sub-tile
            int r = blk8 * 8 + srow;            // 0..127
            int sc = sq ^ (r & 7);              // inverse-swizzled source chunk
            int arow = row0 + r; if (arow > NNODES - 1) arow = NNODES - 1;  // OOB rows unused
            gload_lds16(xsrc + (size_t)arow * FDIM + koff + sc * 8, As + blk8 * 512);
            gload_lds16(Wl + (size_t)r * 256 + kb * 64 + sc * 8, Bs + blk8 * 512);
        }
        __syncthreads();                        // drains vmcnt -> LDS tiles ready
#pragma unroll
        for (int ks = 0; ks < 2; ++ks) {
            bf16x8 a[4], b[4];
            int qr = ks * 4 + (lane >> 4);      // logical chunk 0..7
#pragma unroll
            for (int m = 0; m < 4; ++m) {
                int r = wr * 64 + m * 16 + lr;
                int ch = qr ^ (r & 7);
                a[m] = *(const bf16x8*)&As[r * 64 + ch * 8];
            }
#pragma unroll
            for (int n = 0; n < 4; ++n) {
                int r = wc * 64 + n * 16 + lr;
                int ch = qr ^ (r & 7);
                b[n] = *(const bf16x8*)&Bs[r * 64 + ch * 8];
            }
#pragma unroll
            for (int m = 0; m < 4; ++m)
#pragma unroll
                for (int n = 0; n < 4; ++n)
                    acc[m][n] = __builtin_amdgcn_mfma_f32_16x16x32_bf16(a[m], b[n], acc[m][n], 0, 0, 0);
        }
        __syncthreads();
    }
    // epilogue: bias + relu + bf16, repack via S (aliased Cs)
#pragma unroll
    for (int m = 0; m < 4; ++m) {
#pragma unroll
        for (int n = 0; n < 4; ++n) {
            int col = wc * 64 + n * 16 + lr;
            float bb = bias[col];
#pragma unroll
            for (int reg = 0; reg < 4; ++reg) {
                int row = wr * 64 + m * 16 + (lane >> 4) * 4 + reg;
                float v = fmaxf(acc[m][n][reg] + bb, 0.f);
                S[row * LDC + col] = f2bf(v);
            }
        }
    }
    if (t < 128) batchs[t] = (row0 + t < NNODES) ? batch[row0 + t] : NGRAPHS;
    __syncthreads();
    // coalesced global store
    {
        int r = t >> 1, half = t & 1;
        if (row0 + r < NNODES) {
#pragma unroll
            for (int j = 0; j < 8; ++j) {
                bf16x8 v = *(const bf16x8*)&S[r * LDC + half * 64 + j * 8];
                *(bf16x8*)(houtb + (size_t)(row0 + r) * FDIM + half * 64 + j * 8) = v;
            }
        }
    }
    // fused pool: 2 threads per column, run-length sums + boundary atomics
    {
        int col = t & 127, half = t >> 7;
        int r0 = half * 64, r1 = r0 + 64;
        float* zl = z + (size_t)layer * FDIM + col;
        int g = batchs[r0];
        float s = 0.f;
        for (int r = r0; r < r1; ++r) {
            int gn = batchs[r];
            if (gn != g) {
                atomicAdd(zl + (size_t)g * (NLAYERS * FDIM), s);
                s = 0.f; g = gn;
            }
            s += __uint_as_float((u32)S[r * LDC + col] << 16);   // bf16 -> f32
        }
        atomicAdd(zl + (size_t)g * (NLAYERS * FDIM), s);
    }
}

// ---------------- final MLP (mean normalization folded into z load) ----------------

__global__ __launch_bounds__(128) void mlp1(const float* __restrict__ z,
                                            const int* __restrict__ gptr,
                                            const float* __restrict__ Wl1,
                                            const float* __restrict__ bl1,
                                            float* __restrict__ z2) {
    int g = blockIdx.x, j = threadIdx.x;
    __shared__ float zs[NLAYERS * FDIM];
    int cnt = gptr[g + 1] - gptr[g]; if (cnt < 1) cnt = 1;
    float invc = 1.0f / (float)cnt;
    for (int k = j; k < NLAYERS * FDIM; k += 128)
        zs[k] = z[(size_t)g * (NLAYERS * FDIM) + k] * invc;
    __syncthreads();
    float s = bl1[j];
    for (int k = 0; k < NLAYERS * FDIM; ++k) s = fmaf(zs[k], Wl1[(size_t)k * FDIM + j], s);
    z2[(size_t)g * FDIM + j] = fmaxf(s, 0.f);
}

__global__ __launch_bounds__(128) void mlp2(const float* __restrict__ z2,
                                            const float* __restrict__ Wl2,
                                            const float* __restrict__ bl2,
                                            float* __restrict__ out) {
    int g = blockIdx.x, c = threadIdx.x;
    __shared__ float zs[FDIM];
    if (threadIdx.x < FDIM) zs[threadIdx.x] = z2[(size_t)g * FDIM + threadIdx.x];
    __syncthreads();
    if (c < NCLASS) {
        float s = bl2[c];
        for (int k = 0; k < FDIM; ++k) s = fmaf(zs[k], Wl2[(size_t)k * NCLASS + c], s);
        out[(size_t)g * NCLASS + c] = s;
    }
}

// ---------------- launch ----------------

extern "C" void kernel_launch(void* const* d_in, const int* in_sizes, int n_in,
                              void* d_out, int out_size, void* d_ws, size_t ws_size,
                              hipStream_t stream) {
    const float* x       = (const float*)d_in[0];
    const int*   ei      = (const int*)d_in[1];
    const int*   batch   = (const int*)d_in[2];
    const float* W1_rel  = (const float*)d_in[3];
    const float* b1_rel  = (const float*)d_in[4];
    const float* W1_root = (const float*)d_in[5];
    const float* Wc_rel  = (const float*)d_in[6];
    const float* bc_rel  = (const float*)d_in[7];
    const float* Wc_root = (const float*)d_in[8];
    const float* Wl1     = (const float*)d_in[9];
    const float* bl1     = (const float*)d_in[10];
    const float* Wl2     = (const float*)d_in[11];
    const float* bl2     = (const float*)d_in[12];
    float* out = (float*)d_out;

    const int* srcv = ei;            // edge_index[0]
    const int* dstv = ei + NEDGES;   // edge_index[1]

    char* ws = (char*)d_ws;
    size_t off = 0;
    auto alloc = [&](size_t bytes) -> void* {
        void* p = ws + off;
        off = (off + bytes + 255) & ~(size_t)255;
        return p;
    };
    u16* xb      = (u16*)alloc((size_t)NNODES * FDIM * 2);
    u16* hA      = (u16*)alloc((size_t)NNODES * FDIM * 2);
    u16* hB      = (u16*)alloc((size_t)NNODES * FDIM * 2);
    u16* aggb    = (u16*)alloc((size_t)NNODES * FDIM * 2);
    u16* Wcat    = (u16*)alloc((size_t)NLAYERS * 256 * FDIM * 2);
    int* csr     = (int*)alloc((size_t)NBUCK * EBCAP * 4);
    int* rowstart= (int*)alloc((size_t)NNODES * 4);
    int* rowend  = (int*)alloc((size_t)NNODES * 4);
    int* bcur    = (int*)alloc((size_t)(NBUCK + 1) * 4);
    int* gptr    = (int*)alloc(1024);
    float* z     = (float*)alloc((size_t)(NGRAPHS + 1) * NLAYERS * FDIM * 4);
    float* z2    = (float*)alloc((size_t)NGRAPHS * FDIM * 4);
    // ebuf (16.0 MB) aliases hA+hB region: build completes before layer 0 writes hA
    u64* ebuf    = (u64*)hA;
    (void)ws_size; (void)in_sizes; (void)n_in; (void)out_size;

    hipMemsetAsync(z, 0, (size_t)(NGRAPHS + 1) * NLAYERS * FDIM * 4, stream);
    conv_x<<<(NNODES * FDIM / 4 + 255) / 256, 256, 0, stream>>>(x, xb);
    conv_w<<<(NLAYERS * 256 * FDIM + 255) / 256, 256, 0, stream>>>(W1_rel, W1_root, Wc_rel, Wc_root, Wcat);
    graph_ptr_kernel<<<1, 192, 0, stream>>>(batch, gptr);
    bcur_init<<<(NBUCK + 255) / 256, 256, 0, stream>>>(bcur);
    bucket_scatter<<<NBLK_E, 256, 0, stream>>>(srcv, dstv, bcur, ebuf);
    bucket_csr<<<NBUCK, 256, 0, stream>>>(ebuf, bcur, rowstart, rowend, csr);

    const u16* hin = xb;
    for (int l = 0; l < NLAYERS; ++l) {
        u16* hout = (l & 1) ? hB : hA;
        const u16* Wl = Wcat + (size_t)l * 256 * FDIM;
        const float* bb = (l == 0) ? b1_rel : bc_rel + (size_t)(l - 1) * FDIM;
        agg_bf<<<(NNODES + 3) / 4, 256, 0, stream>>>(hin, rowstart, rowend, csr, aggb);
        gemm_mfma<<<(NNODES + 127) / 128, 256, 0, stream>>>(aggb, hin, Wl, bb, batch, z, l, hout);
        hin = hout;
    }
    mlp1<<<NGRAPHS, 128, 0, stream>>>(z, gptr, Wl1, bl1, z2);
    mlp2<<<NGRAPHS, 128, 0, stream>>>(z2, Wl2, bl2, out);
}